// Round 11
// baseline (685.361 us; speedup 1.0000x reference)
//
#include <hip/hip_runtime.h>

#define DEV __device__ __forceinline__

// ---------- cross-lane helpers ----------

template <int CTRL>
DEV float dppf(float x) {
  return __int_as_float(__builtin_amdgcn_update_dpp(
      0, __float_as_int(x), CTRL, 0xF, 0xF, true));
}

// Butterfly sum within each 32-lane half; broadcast (used only in xsm kernel).
DEV float wsum32(float v) {
  v += dppf<0xB1>(v);
  v += dppf<0x4E>(v);
  v += dppf<0x141>(v);
  v += dppf<0x140>(v);
#if __has_builtin(__builtin_amdgcn_permlane16_swap)
  {
    auto p = __builtin_amdgcn_permlane16_swap(
        __float_as_uint(v), __float_as_uint(v), false, false);
    v = __uint_as_float(p[0]) + __uint_as_float(p[1]);
  }
#else
  v += __shfl_xor(v, 16, 64);
#endif
  return v;
}

// v[l] + v[l^32]
DEV float halfsum(float v) {
#if __has_builtin(__builtin_amdgcn_permlane32_swap)
  auto p = __builtin_amdgcn_permlane32_swap(
      __float_as_uint(v), __float_as_uint(v), false, false);
  return __uint_as_float(p[0]) + __uint_as_float(p[1]);
#else
  return v + __shfl_xor(v, 32, 64);
#endif
}

#define SLEN 1024
#define NH 8
#define DH 32
#define HSTRIDE 2048  // floats per timestep (B*NH*DH)

// ---------- phase 1: x = softmax32(h), staged into d_out ----------

__global__ __launch_bounds__(256)
void srwm_xsm(const float* __restrict__ h, float* __restrict__ x) {
  int i = blockIdx.x * 256 + threadIdx.x;
  float e = __expf(h[i]);
  x[i] = __fdividef(e, wsum32(e));
}

// ---------- phase 2: the scan. One block (4 waves) per (b,h). ----------
// Wave w owns one matrix: 0:Wy 1:Wq 2:Wk 3:wb^T. Lane (r=lane&31, c0) holds
// cols c0..c0+15 of row r (w<3) or wb^T chunk wb[c0+j][r&3] (w==3).
//
// DENORMALIZED-SOFTMAX recurrence (same math as R10, reassociated):
// producers (w1/w2) write UNNORMALIZED eq=exp(aQ), ek=exp(aK) -> one
// transcendental between aA and the barrier (wsum32+fdiv removed from the
// critical chain). Consumers rebuild softmax with scalar fixups computed in
// parallel chains post-read:
//   Sq,Sk   = chunk 16-sums + halfsum      (parallel with matvecs)
//   d       = rcp(Sq)(W.eq) - rcp(Sk)(W.ek)
//   ukr     = BW * d * rcp(Sk)
//   aA      = preA + ukr * (ek . x)
//   W      += ukr (x) ek
// Init eq=ek=1 (so Sq=32, d=0, u=0) -- avoids rcp(0) NaN at step -1.
//
// Shared layout, stride 288B per slot P: eq[32]@0, ek[32]@128B, B[4]@256B.

#define DSR128(dst, addr, off) \
  asm volatile("ds_read_b128 %0, %1 offset:%2" : "=&v"(dst) : "v"(addr), "i"(off))
#define DSR32(dst, addr, off) \
  asm volatile("ds_read_b32 %0, %1 offset:%2" : "=&v"(dst) : "v"(addr), "i"(off))

#define REGION(T, P, EQ, EK, BW, EQN, EKN, BN, XS, XP)                        \
  {                                                                           \
    /* wait for the asm ds_reads issued in the PREVIOUS region */             \
    asm volatile("s_waitcnt lgkmcnt(0)");                                     \
    __builtin_amdgcn_sched_barrier(0);                                        \
    /* ---- parallel chains: chunk sums + 3 matvecs ---- */                   \
    float aq0=0.f,aq1=0.f,aq2=0.f,aq3=0.f;                                    \
    float ak0=0.f,ak1=0.f,ak2=0.f,ak3=0.f;                                    \
    float ex0=0.f,ex1=0.f,ex2=0.f,ex3=0.f;                                    \
    float psq0=0.f,psq1=0.f,psk0=0.f,psk1=0.f;                                \
    _Pragma("unroll") for (int i = 0; i < 4; ++i) {                           \
      float4 qv = EQ[i], kv = EK[i], xv = XS[i];                              \
      aq0 = fmaf(W[4*i+0], qv.x, aq0);                                        \
      aq1 = fmaf(W[4*i+1], qv.y, aq1);                                        \
      aq2 = fmaf(W[4*i+2], qv.z, aq2);                                        \
      aq3 = fmaf(W[4*i+3], qv.w, aq3);                                        \
      ak0 = fmaf(W[4*i+0], kv.x, ak0);                                        \
      ak1 = fmaf(W[4*i+1], kv.y, ak1);                                        \
      ak2 = fmaf(W[4*i+2], kv.z, ak2);                                        \
      ak3 = fmaf(W[4*i+3], kv.w, ak3);                                        \
      ex0 = fmaf(kv.x, xv.x, ex0);                                            \
      ex1 = fmaf(kv.y, xv.y, ex1);                                            \
      ex2 = fmaf(kv.z, xv.z, ex2);                                            \
      ex3 = fmaf(kv.w, xv.w, ex3);                                            \
      psq0 += (qv.x + qv.y); psq1 += (qv.z + qv.w);                           \
      psk0 += (kv.x + kv.y); psk1 += (kv.z + kv.w);                           \
    }                                                                         \
    float Sq = halfsum(psq0 + psq1);                                          \
    float Sk = halfsum(psk0 + psk1);                                          \
    float rq = __fdividef(1.f, Sq);                                           \
    float rk = __fdividef(1.f, Sk);                                           \
    float pd = rq * ((aq0 + aq1) + (aq2 + aq3))                               \
             - rk * ((ak0 + ak1) + (ak2 + ak3));                              \
    float d_   = halfsum(pd);                                                 \
    float ekx  = halfsum((ex0 + ex1) + (ex2 + ex3));                          \
    float ukr  = BW * d_ * rk;                                                \
    float aA   = fmaf(ukr, ekx, preA);                                        \
    /* ---- per-wave nonlinearity + ship (short: one exp, no reduction) */    \
    if (w == 0) {                                                             \
      if (lane < DH) xb[(size_t)(T) * HSTRIDE + lane] = aA;  /* y_T */        \
    } else if (w == 1) {                                                      \
      shb[(P)*72 + r] = __expf(aA);                                           \
    } else if (w == 2) {                                                      \
      shb[(P)*72 + 32 + r] = __expf(aA);                                      \
    } else {                                                                  \
      float sg = __fdividef(1.f, 1.f + __expf(-aA));                          \
      if (lane < 4) shb[(P)*72 + 64 + lane] = sg;                             \
    }                                                                         \
    __builtin_amdgcn_sched_barrier(0);                                        \
    asm volatile("s_waitcnt lgkmcnt(0)");                                     \
    __builtin_amdgcn_sched_barrier(0);                                        \
    __builtin_amdgcn_s_barrier();                                             \
    __builtin_amdgcn_sched_barrier(0);                                        \
    /* ---- pinned async reads of slot P (waited next region) ---- */         \
    DSR128(EQN[0], adC, (P)*288 +   0);                                       \
    DSR128(EQN[1], adC, (P)*288 +  16);                                       \
    DSR128(EQN[2], adC, (P)*288 +  32);                                       \
    DSR128(EQN[3], adC, (P)*288 +  48);                                       \
    DSR128(EKN[0], adC, (P)*288 + 128);                                       \
    DSR128(EKN[1], adC, (P)*288 + 144);                                       \
    DSR128(EKN[2], adC, (P)*288 + 160);                                       \
    DSR128(EKN[3], adC, (P)*288 + 176);                                       \
    DSR32 (BN,    adB, (P)*288 + 256);                                        \
    __builtin_amdgcn_sched_barrier(0);                                        \
    /* ---- hidden under the reads: W<-W_T (uses old ek), prefetch, preA */   \
    _Pragma("unroll") for (int i = 0; i < 4; ++i) {                           \
      float4 kv = EK[i];                                                      \
      W[4*i+0] = fmaf(ukr, kv.x, W[4*i+0]);                                   \
      W[4*i+1] = fmaf(ukr, kv.y, W[4*i+1]);                                   \
      W[4*i+2] = fmaf(ukr, kv.z, W[4*i+2]);                                   \
      W[4*i+3] = fmaf(ukr, kv.w, W[4*i+3]);                                   \
    }                                                                         \
    int t2 = (T) + 2; if (t2 > SLEN - 1) t2 = SLEN - 1;                       \
    { const float* xp_ = xb + (size_t)t2 * HSTRIDE + c0;                      \
      _Pragma("unroll") for (int i = 0; i < 4; ++i)                           \
        XS[i] = *(const float4*)(xp_ + 4 * i); }                              \
    float p0=0.f,p1=0.f,p2=0.f,p3=0.f;                                        \
    _Pragma("unroll") for (int i = 0; i < 4; ++i) {                           \
      float4 xv = XP[i];                                                      \
      p0 = fmaf(W[4*i+0], xv.x, p0);                                          \
      p1 = fmaf(W[4*i+1], xv.y, p1);                                          \
      p2 = fmaf(W[4*i+2], xv.z, p2);                                          \
      p3 = fmaf(W[4*i+3], xv.w, p3);                                          \
    }                                                                         \
    preA = halfsum((p0 + p1) + (p2 + p3));                                    \
  }

__global__ __launch_bounds__(256, 1)
void srwm_scan(const float* __restrict__ Wy0, const float* __restrict__ Wq0,
               const float* __restrict__ Wk0, const float* __restrict__ wb0,
               float* xy) {
  __shared__ float shb[2 * 72];  // slot P: eq@0, ek@32, B@64 (floats)

  const int bh   = blockIdx.x;        // 0..63
  const int hd   = bh & 7;
  const int w    = threadIdx.x >> 6;  // wave: 0..3
  const int lane = threadIdx.x & 63;
  const int r    = lane & 31;
  const int c0   = (lane >> 5) * 16;

  const uint32_t lbase = (uint32_t)(uintptr_t)&shb[0];
  const uint32_t adC   = lbase + c0 * 4;   // chunk reads (eq/ek)
  const uint32_t adB   = lbase + w * 4;    // per-wave beta read

  // ---- load this wave's matrix ----
  float W[16];
  if (w < 3) {
    const float* src = (w == 0) ? Wy0 : (w == 1) ? Wq0 : Wk0;
    const float* p = src + (hd * DH + r) * DH + c0;
#pragma unroll
    for (int j = 0; j < 16; j += 4) *(float4*)&W[j] = *(const float4*)(p + j);
  } else {
    const int kk = r & 3;
#pragma unroll
    for (int j = 0; j < 16; ++j) W[j] = wb0[(hd * DH + c0 + j) * 4 + kk];
  }

  float* xb = xy + bh * DH;  // x/y for this (b,h): element [t*HSTRIDE + j]

  // ---- prologue: X0 <- x_0, X1 <- x_1; eq_{-1}=ek_{-1}=1 (d=0, u=0),
  //      B_{-1}=0; preA = W_0 x_0 ----
  float4 X0[4], X1[4];
#pragma unroll
  for (int i = 0; i < 4; ++i) {
    X0[i] = *(const float4*)(xb + c0 + 4 * i);
    X1[i] = *(const float4*)(xb + HSTRIDE + c0 + 4 * i);
  }
  float p0 = 0.f, p1 = 0.f, p2 = 0.f, p3 = 0.f;
#pragma unroll
  for (int i = 0; i < 4; ++i) {
    float4 xv = X0[i];
    p0 = fmaf(W[4*i+0], xv.x, p0);
    p1 = fmaf(W[4*i+1], xv.y, p1);
    p2 = fmaf(W[4*i+2], xv.z, p2);
    p3 = fmaf(W[4*i+3], xv.w, p3);
  }
  float preA = halfsum((p0 + p1) + (p2 + p3));

  float4 QA[4], KA[4], QB[4], KB[4];
  const float4 one4 = {1.f, 1.f, 1.f, 1.f};
#pragma unroll
  for (int i = 0; i < 4; ++i) { QA[i] = one4; KA[i] = one4; }
  float BwA = 0.f, BwB = 0.f;

  __syncthreads();

  for (int t = 0; t < SLEN; t += 2) {
    REGION(t,     0, QA, KA, BwA, QB, KB, BwB, X0, X1);
    REGION(t + 1, 1, QB, KB, BwB, QA, KA, BwA, X1, X0);
  }
}

// ---------- phase 3: out = h + ys @ Wout^T  (in-place over ys==out) ----------

__global__ __launch_bounds__(256)
void srwm_proj(const float* __restrict__ h, const float* __restrict__ ys,
               const float* __restrict__ Wout, float* __restrict__ out) {
  __shared__ float ytile[32][256];  // 32 KB
  const int r0  = blockIdx.x * 32;
  const int tid = threadIdx.x;

  const float4* src = (const float4*)(ys + (size_t)r0 * 256);
  float4*       dst = (float4*)(&ytile[0][0]);
#pragma unroll
  for (int i = 0; i < 8; ++i) dst[tid + i * 256] = src[tid + i * 256];
  __syncthreads();

  float acc[32];
#pragma unroll
  for (int m = 0; m < 32; ++m) acc[m] = 0.f;

  const float* wrow = Wout + (size_t)tid * 256;
  for (int k = 0; k < 256; k += 4) {
    float4 wv = *(const float4*)(wrow + k);
#pragma unroll
    for (int m = 0; m < 32; ++m) {
      float4 y4 = *(const float4*)(&ytile[m][k]);
      acc[m] = fmaf(wv.x, y4.x,
               fmaf(wv.y, y4.y,
               fmaf(wv.z, y4.z,
               fmaf(wv.w, y4.w, acc[m]))));
    }
  }

#pragma unroll
  for (int m = 0; m < 32; ++m) {
    int row = r0 + m;
    out[(size_t)row * 256 + tid] = h[(size_t)row * 256 + tid] + acc[m];
  }
}

// ---------- launcher ----------

extern "C" void kernel_launch(void* const* d_in, const int* in_sizes, int n_in,
                              void* d_out, int out_size, void* d_ws, size_t ws_size,
                              hipStream_t stream) {
  const float* h    = (const float*)d_in[0];
  const float* Wy0  = (const float*)d_in[1];
  const float* Wq0  = (const float*)d_in[2];
  const float* Wk0  = (const float*)d_in[3];
  const float* wb0  = (const float*)d_in[4];
  const float* Wout = (const float*)d_in[5];
  float* out = (float*)d_out;

  // d_out triple duty: x (phase1) -> progressively overwritten by y (phase2)
  // -> final output (phase3, in-place via LDS tile).
  srwm_xsm <<<SLEN * HSTRIDE / 256, 256, 0, stream>>>(h, out);
  srwm_scan<<<64, 256, 0, stream>>>(Wy0, Wq0, Wk0, wb0, out);
  srwm_proj<<<256, 256, 0, stream>>>(h, out, Wout, out);
}